// Round 5
// baseline (322.272 us; speedup 1.0000x reference)
//
#include <hip/hip_runtime.h>

#define NROWS  32768
#define DIM    64
#define KCODES 1024
#define NELEM  (NROWS * DIM)      // 2097152
#define CHUNKS 8
#define CPC    128                // codes per chunk
#define NBLK_B 512                // vq_out blocks
#define RPB_B  64                 // rows per vq_out block

typedef float v2f __attribute__((ext_vector_type(2)));

// numpy pairwise sum-of-squares over a 64-float row loaded from memory:
// 8 accumulators, r[k] sums v[8i+k] over i, combine
// ((r0+r1)+(r2+r3))+((r4+r5)+(r6+r7)). contract(off): numpy squares into a
// temp then sums — no FMA fusion. Verified bit-exact rounds 1-4 (absmax 0.0).
__device__ __forceinline__ float np_sumsq_f4(const float4* __restrict__ p) {
#pragma clang fp contract(off)
  float4 a = p[0], b = p[1];
  float r0 = a.x * a.x, r1 = a.y * a.y, r2 = a.z * a.z, r3 = a.w * a.w;
  float r4 = b.x * b.x, r5 = b.y * b.y, r6 = b.z * b.z, r7 = b.w * b.w;
#pragma unroll
  for (int i = 1; i < 8; ++i) {
    a = p[2 * i]; b = p[2 * i + 1];
    r0 += a.x * a.x; r1 += a.y * a.y; r2 += a.z * a.z; r3 += a.w * a.w;
    r4 += b.x * b.x; r5 += b.y * b.y; r6 += b.z * b.z; r7 += b.w * b.w;
  }
  return ((r0 + r1) + (r2 + r3)) + ((r4 + r5) + (r6 + r7));
}

// Same arithmetic, same order, but from the resident xv[32] v2f registers
// (xv[4i]={p2i.x,p2i.y}, xv[4i+1]={p2i.z,p2i.w}, xv[4i+2]={p2i+1.x,y}, ...).
// Single load site for x: fill xv once, pin, derive sx from registers.
__device__ __forceinline__ float np_sumsq_reg(const v2f xv[32]) {
#pragma clang fp contract(off)
  float r0 = xv[0].x * xv[0].x, r1 = xv[0].y * xv[0].y;
  float r2 = xv[1].x * xv[1].x, r3 = xv[1].y * xv[1].y;
  float r4 = xv[2].x * xv[2].x, r5 = xv[2].y * xv[2].y;
  float r6 = xv[3].x * xv[3].x, r7 = xv[3].y * xv[3].y;
#pragma unroll
  for (int i = 1; i < 8; ++i) {
    r0 += xv[4 * i + 0].x * xv[4 * i + 0].x;
    r1 += xv[4 * i + 0].y * xv[4 * i + 0].y;
    r2 += xv[4 * i + 1].x * xv[4 * i + 1].x;
    r3 += xv[4 * i + 1].y * xv[4 * i + 1].y;
    r4 += xv[4 * i + 2].x * xv[4 * i + 2].x;
    r5 += xv[4 * i + 2].y * xv[4 * i + 2].y;
    r6 += xv[4 * i + 3].x * xv[4 * i + 3].x;
    r7 += xv[4 * i + 3].y * xv[4 * i + 3].y;
  }
  return ((r0 + r1) + (r2 + r3)) + ((r4 + r5) + (r6 + r7));
}

// Kernel A: fused se-prep + distances + per-chunk argmin.
// Grid 1024 = 128 row-groups x 8 K-chunks, one thread per row.
// REGISTER BUDGET (the rounds-2..4 lesson): at (256,4) the budget is 128.
// xv(64, pinned) + w-in-flight(16..32: VMEM path, no unroll pragma) + acc(8)
// + misc(~15) ~= 110 — closes. Rounds 2-4 failed because w on the SGPR path
// + unroll-2 put 64 more regs in flight -> allocator spilled xv to scratch
// (VGPR_Count 40/44/52 < the 64 that must be resident).
// w goes through VMEM on purpose: `vzero` (opaque v_mov_b32) defeats
// uniformity analysis, so addresses are formally divergent ->
// global_load_dwordx4 with 16+ outstanding slots, L1-resident 32 KB chunk,
// same-address-across-wave loads coalesce to one line. The SGPR file (~102)
// could hold only ~1.5 codes of w -> no pipelining on the scalar path.
// d = fmaf(-2, dot, fl(sx+se[c])) — bit-exact vs ref's fl(fl(sx+se)-fl(2dot))
// since fl(2*dot) is exact. Ascending strict-< scan keeps lowest index on
// in-chunk ties; cross-chunk ties via u64 key min (index in low bits).
__global__ __launch_bounds__(256, 4) void vq_dist(const float* __restrict__ x,
                                                  const float* __restrict__ w,
                                                  unsigned long long* __restrict__ keys,
                                                  double* __restrict__ loss,
                                                  unsigned int* __restrict__ cnt) {
  __shared__ float se[CPC];
  const int t = threadIdx.x;
  const int g = blockIdx.x >> 3;
  const int chunk = blockIdx.x & 7;
  const int c0 = chunk * CPC;

  if (blockIdx.x == 0 && t == 0) { *loss = 0.0; *cnt = 0u; }

  // se for this chunk's 128 codes (numpy pairwise rounding).
  if (t < CPC)
    se[t] = np_sumsq_f4((const float4*)(w + (size_t)(c0 + t) * DIM));

  // Opaque zero in a VGPR: forces the w-load path to VMEM (see header).
  int vzero;
  asm volatile("v_mov_b32 %0, 0" : "=v"(vzero));

  const int row = g * 256 + t;
  const float4* xr = (const float4*)(x + (size_t)row * DIM);

  // Single load site for x; resident row = 32 v2f = 64 VGPRs, pinned.
  v2f xv[32];
#pragma unroll
  for (int i = 0; i < 16; ++i) {
    float4 q = xr[i];
    xv[2 * i + 0] = (v2f){q.x, q.y};
    xv[2 * i + 1] = (v2f){q.z, q.w};
  }
#pragma unroll
  for (int i = 0; i < 32; ++i) asm volatile("" : "+v"(xv[i]));

  const float sx = np_sumsq_reg(xv);
  __syncthreads();

  const float4* wbase = (const float4*)w + vzero;   // divergent -> VMEM
  float best_d = 3.4e38f;
  int best_c = c0;

  for (int j = 0; j < CPC; ++j) {
    const int c = c0 + j;
    const float4* wr = wbase + ((size_t)c << 4);
    v2f a0 = (v2f){0.f, 0.f}, a1 = (v2f){0.f, 0.f};
    v2f a2 = (v2f){0.f, 0.f}, a3 = (v2f){0.f, 0.f};
#pragma unroll
    for (int i = 0; i < 16; i += 2) {
      float4 q0 = wr[i];
      float4 q1 = wr[i + 1];
      a0 += (v2f){q0.x, q0.y} * xv[2 * i + 0];   // v_pk_fma_f32
      a1 += (v2f){q0.z, q0.w} * xv[2 * i + 1];
      a2 += (v2f){q1.x, q1.y} * xv[2 * i + 2];
      a3 += (v2f){q1.z, q1.w} * xv[2 * i + 3];
    }
    v2f s = (a0 + a1) + (a2 + a3);
    float dot = s.x + s.y;
    float ad = sx + se[j];
    float d = fmaf(-2.0f, dot, ad);
    if (d < best_d) { best_d = d; best_c = c; }
  }

  keys[((size_t)row << 3) | chunk] =
      ((unsigned long long)__float_as_uint(best_d) << 32) | (unsigned int)best_c;
}

// Kernel B: 8-way key min -> index; indices (as float), STE quantized output
// x + fl(w - x) (bit-exact ref forward), fp64 loss shuffle-reduce + one
// atomic/block; last block (device counter) finalizes commitment loss.
__global__ __launch_bounds__(256) void vq_out(const float* __restrict__ x,
                                              const float* __restrict__ w,
                                              const unsigned long long* __restrict__ keys,
                                              float* __restrict__ outq,
                                              float* __restrict__ outidx,
                                              double* __restrict__ loss,
                                              unsigned int* __restrict__ cnt,
                                              float* __restrict__ outloss) {
  __shared__ int sidx[RPB_B];
  __shared__ double part[4];
  const int b = blockIdx.x, t = threadIdx.x;

  if (t < RPB_B) {
    const int row = b * RPB_B + t;
    const unsigned long long* kr = keys + ((size_t)row << 3);
    unsigned long long m = kr[0];
#pragma unroll
    for (int i = 1; i < 8; ++i) { unsigned long long k = kr[i]; if (k < m) m = k; }
    const int idx = (int)(unsigned int)(m & 0xFFFFFFFFull);
    outidx[row] = (float)idx;
    sidx[t] = idx;
  }
  __syncthreads();

  double acc = 0.0;
  const float4* x4 = (const float4*)x;
  float4* o4 = (float4*)outq;
#pragma unroll
  for (int i = 0; i < 4; ++i) {
    const int e = i * 256 + t;          // 0..1023 float4s of this block's rows
    const int rl = e >> 4;              // local row (0..63)
    const int d4 = e & 15;
    const size_t gofs = ((size_t)b * RPB_B + rl) * 16 + d4;
    float4 xvv = x4[gofs];
    const float4* wr = (const float4*)(w + (size_t)sidx[rl] * DIM);
    float4 wv = wr[d4];
    float tx = wv.x - xvv.x, ty = wv.y - xvv.y;
    float tz = wv.z - xvv.z, tw = wv.w - xvv.w;
    float4 q;
    q.x = xvv.x + tx; q.y = xvv.y + ty;   // ref STE: x + fl(q - x)
    q.z = xvv.z + tz; q.w = xvv.w + tw;
    o4[gofs] = q;
    acc += (double)tx * tx + (double)ty * ty + (double)tz * tz + (double)tw * tw;
  }

#pragma unroll
  for (int s = 32; s > 0; s >>= 1) acc += __shfl_down(acc, s, 64);
  if ((t & 63) == 0) part[t >> 6] = acc;
  __syncthreads();
  if (t == 0) {
    atomicAdd(loss, (part[0] + part[1]) + (part[2] + part[3]));
    __threadfence();
    unsigned int old = atomicAdd(cnt, 1u);
    if (old == NBLK_B - 1) {
      double L = atomicAdd(loss, 0.0);   // all adds happened-before
      *outloss = 0.5f * (float)(L / (double)NELEM);
    }
  }
}

extern "C" void kernel_launch(void* const* d_in, const int* in_sizes, int n_in,
                              void* d_out, int out_size, void* d_ws, size_t ws_size,
                              hipStream_t stream) {
  const float* x = (const float*)d_in[0];   // inputs (32,64,32,32) fp32
  const float* w = (const float*)d_in[1];   // weight (1024,64) fp32

  float* outq    = (float*)d_out;           // [0, 2097152)
  float* outidx  = outq + NELEM;            // [2097152, +32768)
  float* outloss = outidx + NROWS;          // [2129920]

  char* wsb = (char*)d_ws;
  double* loss = (double*)wsb;                                   // 8 B
  unsigned int* cnt = (unsigned int*)(wsb + 64);                 // 4 B
  unsigned long long* keys = (unsigned long long*)(wsb + 256);   // 2 MB

  hipLaunchKernelGGL(vq_dist, dim3(1024),  dim3(256), 0, stream,
                     x, w, keys, loss, cnt);
  hipLaunchKernelGGL(vq_out,  dim3(NBLK_B), dim3(256), 0, stream,
                     x, w, keys, outq, outidx, loss, cnt, outloss);
}

// Round 6
// 143.566 us; speedup vs baseline: 2.2448x; 2.2448x over previous
//
#include <hip/hip_runtime.h>

#define NROWS  32768
#define DIM    64
#define KCODES 1024
#define NELEM  (NROWS * DIM)      // 2097152
#define NBLK_B 512                // vq_out blocks
#define RPB_B  64                 // rows per vq_out block

typedef float v2f __attribute__((ext_vector_type(2)));

// numpy pairwise sum-of-squares over a 64-float row: 8 accumulators, r[k]
// sums v[8i+k] over i, combine ((r0+r1)+(r2+r3))+((r4+r5)+(r6+r7)).
// contract(off): numpy squares into a temp then sums — no FMA fusion.
// Verified bit-exact rounds 1-5 (absmax 0.0).
__device__ __forceinline__ float np_sumsq_f4(const float4* __restrict__ p) {
#pragma clang fp contract(off)
  float4 a = p[0], b = p[1];
  float r0 = a.x * a.x, r1 = a.y * a.y, r2 = a.z * a.z, r3 = a.w * a.w;
  float r4 = b.x * b.x, r5 = b.y * b.y, r6 = b.z * b.z, r7 = b.w * b.w;
#pragma unroll
  for (int i = 1; i < 8; ++i) {
    a = p[2 * i]; b = p[2 * i + 1];
    r0 += a.x * a.x; r1 += a.y * a.y; r2 += a.z * a.z; r3 += a.w * a.w;
    r4 += b.x * b.x; r5 += b.y * b.y; r6 += b.z * b.z; r7 += b.w * b.w;
  }
  return ((r0 + r1) + (r2 + r3)) + ((r4 + r5) + (r6 + r7));
}

// Prep: per-row ||x||^2, per-code ||e||^2 (numpy pairwise rounding), zero
// loss/cnt. Grid 128 x 256.
__global__ __launch_bounds__(256) void vq_prep(const float* __restrict__ x,
                                               const float* __restrict__ w,
                                               float* __restrict__ sxv,
                                               float* __restrict__ se,
                                               double* __restrict__ loss,
                                               unsigned int* __restrict__ cnt) {
  const int t = blockIdx.x * 256 + threadIdx.x;
  if (t == 0) { *loss = 0.0; *cnt = 0u; }
  sxv[t] = np_sumsq_f4((const float4*)(x + (size_t)t * DIM));
  if (t < KCODES) se[t] = np_sumsq_f4((const float4*)(w + (size_t)t * DIM));
}

// vq_dist: LDS-tiled GEMM. The rounds-2..5 lesson: this backend's allocator
// spills/demotes LOAD-derived register arrays (xv row cache: VGPR stuck at
// 40/44/52 four rounds straight) but allocates ACCUMULATOR arrays fine
// (m97 precedent: 64 f32 accs at VGPR=164). So the big per-thread array is
// now the accumulator of a classic 128x128-tile GEMM over K=64.
//   grid 2048 = 256 row-groups x 8 code-chunks; block 256 thr = 4 waves.
//   LDS: xs[128][64] row-major, float4-slot swizzle (f4 ^ (row&15)) — makes
//        both the staging stores and the per-iteration b128 fragment reads
//        <=2-way bank aliased (free, m136);
//        ws[64][128] k-major, code-group swizzle ((c>>2) ^ (k&31)) — reads
//        are 4-unique-address broadcasts (free); staging stores are 8-way
//        conflicted but run ONCE per block (~100 cyc, negligible).
//   Thread tile: rows (t&15)+16j (j=0..7), codes 4a+{0..3} and 64+4a+{0..3}
//   (a=t>>4). acc[8][4] v2f, code-paired -> v_pk_fma_f32 with x splat.
//   Each code's dot = one sequential-k FMA chain (dot-order insensitivity
//   verified: absmax 0.0 across 4 different orders, rounds 1-5).
// d = fmaf(-2, dot, fl(sx+se[c])) — bit-exact vs ref's fl(fl(sx+se)-fl(2dot)).
// Argmin: ascending-code strict-< scan per thread -> u64 (dist_bits<<32|code)
// LDS min over the 16 threads per row -> per-chunk slot; vq_out does the
// cross-chunk 8-way min (distances positive -> fp32 bits monotone).
__global__ __launch_bounds__(256, 2) void vq_dist(const float* __restrict__ x,
                                                  const float* __restrict__ w,
                                                  const float* __restrict__ sxv,
                                                  const float* __restrict__ seg,
                                                  unsigned long long* __restrict__ keys) {
  __shared__ float xs[128 * 64];   // 32 KB
  __shared__ float ws[64 * 128];   // 32 KB  (total 64 KB -> 2 blocks/CU)
  const int t = threadIdx.x;
  const int rg = blockIdx.x >> 3;
  const int cc = blockIdx.x & 7;
  const int row0 = rg * 128;
  const int c0 = cc * 128;

  // ---- stage tiles (coalesced global float4 loads) ----
  {
    const float4* xg = (const float4*)x + (size_t)row0 * 16;
    const float4* wg = (const float4*)w + (size_t)c0 * 16;
    float4* xs4 = (float4*)xs;
#pragma unroll
    for (int i = 0; i < 8; ++i) {
      const int g = t + 256 * i;           // 0..2047
      const int rr = g >> 4, f4 = g & 15;
      xs4[rr * 16 + (f4 ^ (rr & 15))] = xg[g];
      float4 u = wg[g];                    // code rr, k-group f4 (reuse rr/f4)
      const int k0 = f4 * 4;
      const int clo = rr & 3, chi = rr >> 2;
      ws[(k0 + 0) * 128 + ((chi ^ ((k0 + 0) & 31)) << 2) + clo] = u.x;
      ws[(k0 + 1) * 128 + ((chi ^ ((k0 + 1) & 31)) << 2) + clo] = u.y;
      ws[(k0 + 2) * 128 + ((chi ^ ((k0 + 2) & 31)) << 2) + clo] = u.z;
      ws[(k0 + 3) * 128 + ((chi ^ ((k0 + 3) & 31)) << 2) + clo] = u.w;
    }
  }
  __syncthreads();

  const int m = t & 15, a = t >> 4;
  v2f acc[8][4];
#pragma unroll
  for (int j = 0; j < 8; ++j)
#pragma unroll
    for (int p = 0; p < 4; ++p) acc[j][p] = (v2f){0.f, 0.f};

  const float4* xs4 = (const float4*)xs;
  const float4* ws4 = (const float4*)ws;

#pragma unroll 2
  for (int kb = 0; kb < 16; ++kb) {
    float4 xf[8];
#pragma unroll
    for (int j = 0; j < 8; ++j)
      xf[j] = xs4[(m + 16 * j) * 16 + (kb ^ m)];
    v2f wf[4][4];
#pragma unroll
    for (int kk = 0; kk < 4; ++kk) {
      const int k = kb * 4 + kk, sw = k & 31;
      float4 u0 = ws4[k * 32 + (a ^ sw)];          // codes 4a..4a+3
      float4 u1 = ws4[k * 32 + ((a + 16) ^ sw)];   // codes 64+4a..+3
      wf[kk][0] = (v2f){u0.x, u0.y}; wf[kk][1] = (v2f){u0.z, u0.w};
      wf[kk][2] = (v2f){u1.x, u1.y}; wf[kk][3] = (v2f){u1.z, u1.w};
    }
#pragma unroll
    for (int j = 0; j < 8; ++j) {
#pragma unroll
      for (int p = 0; p < 4; ++p) {
        acc[j][p] += (v2f){xf[j].x, xf[j].x} * wf[0][p];   // v_pk_fma_f32
        acc[j][p] += (v2f){xf[j].y, xf[j].y} * wf[1][p];
        acc[j][p] += (v2f){xf[j].z, xf[j].z} * wf[2][p];
        acc[j][p] += (v2f){xf[j].w, xf[j].w} * wf[3][p];
      }
    }
  }

  // ---- epilogue: per-thread best key per row (ascending codes) ----
  unsigned long long bk[8];
#pragma unroll
  for (int j = 0; j < 8; ++j) {
    const float sx = sxv[row0 + m + 16 * j];
    unsigned long long best = ~0ull;
#pragma unroll
    for (int p = 0; p < 4; ++p) {
      const int cb = c0 + 4 * a + ((p < 2) ? 2 * p : 64 + 2 * (p - 2));
      const float d0 = fmaf(-2.0f, acc[j][p].x, sx + seg[cb]);
      const float d1 = fmaf(-2.0f, acc[j][p].y, sx + seg[cb + 1]);
      const unsigned long long k0v =
          ((unsigned long long)__float_as_uint(d0) << 32) | (unsigned int)cb;
      const unsigned long long k1v =
          ((unsigned long long)__float_as_uint(d1) << 32) | (unsigned int)(cb + 1);
      if (k0v < best) best = k0v;
      if (k1v < best) best = k1v;
    }
    bk[j] = best;
  }

  // ---- cross-thread per-row reduce (reuse xs as scratch after barrier) ----
  __syncthreads();
  unsigned long long* kred = (unsigned long long*)xs;   // 128*17 u64 = 17 KB
#pragma unroll
  for (int j = 0; j < 8; ++j) kred[(m + 16 * j) * 17 + a] = bk[j];
  __syncthreads();
  if (t < 128) {
    unsigned long long mn = kred[t * 17];
#pragma unroll
    for (int q = 1; q < 16; ++q) {
      const unsigned long long kq = kred[t * 17 + q];
      if (kq < mn) mn = kq;
    }
    keys[((size_t)(row0 + t) << 3) | cc] = mn;
  }
}

// vq_out: 8-way key min -> index; indices (as float), STE quantized output
// x + fl(w - x) (bit-exact ref forward), fp64 loss shuffle-reduce + one
// atomic/block; last block (device counter) finalizes commitment loss.
// Unchanged from rounds 4-5 (verified absmax 0.0).
__global__ __launch_bounds__(256) void vq_out(const float* __restrict__ x,
                                              const float* __restrict__ w,
                                              const unsigned long long* __restrict__ keys,
                                              float* __restrict__ outq,
                                              float* __restrict__ outidx,
                                              double* __restrict__ loss,
                                              unsigned int* __restrict__ cnt,
                                              float* __restrict__ outloss) {
  __shared__ int sidx[RPB_B];
  __shared__ double part[4];
  const int b = blockIdx.x, t = threadIdx.x;

  if (t < RPB_B) {
    const int row = b * RPB_B + t;
    const unsigned long long* kr = keys + ((size_t)row << 3);
    unsigned long long mn = kr[0];
#pragma unroll
    for (int i = 1; i < 8; ++i) { unsigned long long k = kr[i]; if (k < mn) mn = k; }
    const int idx = (int)(unsigned int)(mn & 0xFFFFFFFFull);
    outidx[row] = (float)idx;
    sidx[t] = idx;
  }
  __syncthreads();

  double acc = 0.0;
  const float4* x4 = (const float4*)x;
  float4* o4 = (float4*)outq;
#pragma unroll
  for (int i = 0; i < 4; ++i) {
    const int e = i * 256 + t;
    const int rl = e >> 4;
    const int d4 = e & 15;
    const size_t gofs = ((size_t)b * RPB_B + rl) * 16 + d4;
    float4 xvv = x4[gofs];
    const float4* wr = (const float4*)(w + (size_t)sidx[rl] * DIM);
    float4 wv = wr[d4];
    float tx = wv.x - xvv.x, ty = wv.y - xvv.y;
    float tz = wv.z - xvv.z, tw = wv.w - xvv.w;
    float4 q;
    q.x = xvv.x + tx; q.y = xvv.y + ty;   // ref STE: x + fl(q - x)
    q.z = xvv.z + tz; q.w = xvv.w + tw;
    o4[gofs] = q;
    acc += (double)tx * tx + (double)ty * ty + (double)tz * tz + (double)tw * tw;
  }

#pragma unroll
  for (int s = 32; s > 0; s >>= 1) acc += __shfl_down(acc, s, 64);
  if ((t & 63) == 0) part[t >> 6] = acc;
  __syncthreads();
  if (t == 0) {
    atomicAdd(loss, (part[0] + part[1]) + (part[2] + part[3]));
    __threadfence();
    unsigned int old = atomicAdd(cnt, 1u);
    if (old == NBLK_B - 1) {
      double L = atomicAdd(loss, 0.0);   // all adds happened-before
      *outloss = 0.5f * (float)(L / (double)NELEM);
    }
  }
}

extern "C" void kernel_launch(void* const* d_in, const int* in_sizes, int n_in,
                              void* d_out, int out_size, void* d_ws, size_t ws_size,
                              hipStream_t stream) {
  const float* x = (const float*)d_in[0];   // inputs (32,64,32,32) fp32
  const float* w = (const float*)d_in[1];   // weight (1024,64) fp32

  float* outq    = (float*)d_out;           // [0, 2097152)
  float* outidx  = outq + NELEM;            // [2097152, +32768)
  float* outloss = outidx + NROWS;          // [2129920]

  char* wsb = (char*)d_ws;
  double* loss = (double*)wsb;                                     // @0
  unsigned int* cnt = (unsigned int*)(wsb + 64);                   // @64
  float* sxv = (float*)(wsb + 4096);                               // 128 KB
  float* se  = (float*)(wsb + 4096 + 131072);                      // 4 KB
  unsigned long long* keys = (unsigned long long*)(wsb + 139264);  // 2 MB

  hipLaunchKernelGGL(vq_prep, dim3(128),  dim3(256), 0, stream,
                     x, w, sxv, se, loss, cnt);
  hipLaunchKernelGGL(vq_dist, dim3(2048), dim3(256), 0, stream,
                     x, w, sxv, se, keys);
  hipLaunchKernelGGL(vq_out,  dim3(NBLK_B), dim3(256), 0, stream,
                     x, w, keys, outq, outidx, loss, cnt, outloss);
}